// Round 1
// baseline (6484.695 us; speedup 1.0000x reference)
//
#include <hip/hip_runtime.h>

#define HH 96
#define WW 96
#define CC 21
#define NN (HH*WW)          // 9216
#define NBLK (NN/256)       // 36

// ---------------------------------------------------------------------------
// ws layout (floats):
//   U       [NN*CC]          unary potentials, pixel-major [i][c]
//   Qa      [NN*CC]          Q ping
//   Qb      [NN*CC]          Q pong
//   feats   [NN*8]           {y/64, x/64, y/3, x/3, r/255, g/255, b/255, 0}
//   partial [64]             per-block CE partial sums (NBLK used)
//   ce      [1]
// total ~2.62 MB
// ---------------------------------------------------------------------------

__global__ __launch_bounds__(256) void k_setup(
    const float* __restrict__ logits, const int* __restrict__ labels,
    const float* __restrict__ image, float* __restrict__ U,
    float* __restrict__ Q0, float* __restrict__ feats,
    float* __restrict__ partial) {
  const int t = threadIdx.x;
  const int i = blockIdx.x * 256 + t;

  float d[CC];
  float mx = -1e30f;
#pragma unroll
  for (int c = 0; c < CC; ++c) {
    d[c] = logits[c * NN + i];
    mx = fmaxf(mx, d[c]);
  }
  float s = 0.f;
#pragma unroll
  for (int c = 0; c < CC; ++c) {
    d[c] -= mx;                  // shifted logits
    s += __expf(d[c]);
  }
  const float lse = logf(s);
  const float inv = 1.f / s;
  const int lab = labels[i];
  float myU = 0.f;
#pragma unroll
  for (int c = 0; c < CC; ++c) {
    const float Uc = lse - d[c];          // -logp
    U[i * CC + c] = Uc;
    Q0[i * CC + c] = __expf(d[c]) * inv;  // softmax(logits) == softmax(logp)
    myU = (c == lab) ? Uc : myU;
  }

  // features, pre-scaled
  const float fy = (float)(i / WW), fx = (float)(i % WW);
  const float r = image[i], g = image[NN + i], b = image[2 * NN + i];
  float* f = feats + i * 8;
  f[0] = fy * (1.f / 64.f);  f[1] = fx * (1.f / 64.f);
  f[2] = fy * (1.f / 3.f);   f[3] = fx * (1.f / 3.f);
  f[4] = r * (1.f / 255.f);  f[5] = g * (1.f / 255.f);
  f[6] = b * (1.f / 255.f);  f[7] = 0.f;

  // deterministic block reduction of CE contributions
  __shared__ float red[256];
  red[t] = myU;
  __syncthreads();
  for (int off = 128; off > 0; off >>= 1) {
    if (t < off) red[t] += red[t + off];
    __syncthreads();
  }
  if (t == 0) partial[blockIdx.x] = red[0];
}

__global__ void k_reduce_ce(const float* __restrict__ partial,
                            float* __restrict__ ce) {
  float v = (threadIdx.x < NBLK) ? partial[threadIdx.x] : 0.f;
#pragma unroll
  for (int off = 32; off > 0; off >>= 1) v += __shfl_down(v, off);
  if (threadIdx.x == 0) ce[0] = v * (1.f / (float)NN);
}

// one mean-field iteration: Qout = softmax(-U - 10*(rowsum(msg) - msg)),
// msg = (Kg + Kb) @ Qin  with self-connection removed.
__global__ __launch_bounds__(256) void k_mf(
    const float* __restrict__ U, const float* __restrict__ Qin,
    const float* __restrict__ feats, float* __restrict__ Qout) {
  const int t = threadIdx.x;
  const int i = blockIdx.x * 256 + t;

  const float* fi = feats + i * 8;
  const float f0 = fi[0], f1 = fi[1], f2 = fi[2], f3 = fi[3];
  const float f4 = fi[4], f5 = fi[5], f6 = fi[6];

  float msg[CC];
#pragma unroll
  for (int c = 0; c < CC; ++c) msg[c] = 0.f;

  __shared__ float sQ[128][24];   // padded to 24 for 16B-aligned ds_read_b128
  __shared__ float sF[128][8];

  for (int base = 0; base < NN; base += 128) {
    __syncthreads();
    // stage 128 Q rows (128*21 = 2688 floats)
    const float* qsrc = Qin + base * CC;
    for (int idx = t; idx < 128 * CC; idx += 256) {
      const int r = idx / CC;
      sQ[r][idx - r * CC] = qsrc[idx];
    }
    // stage 128 feature rows (flat copy, already padded to 8)
    const float* fsrc = feats + base * 8;
    float* sFf = &sF[0][0];
    for (int idx = t; idx < 128 * 8; idx += 256) sFf[idx] = fsrc[idx];
    __syncthreads();

#pragma unroll 2
    for (int jj = 0; jj < 128; ++jj) {
      const float dy = f0 - sF[jj][0];
      const float dx = f1 - sF[jj][1];
      const float d2g = dy * dy + dx * dx;
      const float a0 = f2 - sF[jj][2];
      const float a1 = f3 - sF[jj][3];
      const float a2 = f4 - sF[jj][4];
      const float a3 = f5 - sF[jj][5];
      const float a4 = f6 - sF[jj][6];
      const float d2b = a0 * a0 + a1 * a1 + a2 * a2 + a3 * a3 + a4 * a4;
      const float w = __expf(-0.5f * d2g) + __expf(-0.5f * d2b);
#pragma unroll
      for (int c = 0; c < CC; ++c) msg[c] = fmaf(w, sQ[jj][c], msg[c]);
    }
  }

  // remove self-connection (both kernels contribute exp(0)=1 at j==i)
  float tot = 0.f;
#pragma unroll
  for (int c = 0; c < CC; ++c) {
    msg[c] -= 2.f * Qin[i * CC + c];
    tot += msg[c];
  }
  // new logits: -U - COMPAT*(tot - msg_c); reuse msg[] as logits, then probs
  float mx = -1e30f;
#pragma unroll
  for (int c = 0; c < CC; ++c) {
    const float l = -U[i * CC + c] - 10.f * (tot - msg[c]);
    msg[c] = l;
    mx = fmaxf(mx, l);
  }
  float s = 0.f;
#pragma unroll
  for (int c = 0; c < CC; ++c) {
    const float e = __expf(msg[c] - mx);
    msg[c] = e;
    s += e;
  }
  const float inv = 1.f / s;
#pragma unroll
  for (int c = 0; c < CC; ++c) Qout[i * CC + c] = msg[c] * inv;
}

__global__ __launch_bounds__(256) void k_out(
    const float* __restrict__ Q, const float* __restrict__ ce,
    float* __restrict__ out) {
  const int idx = blockIdx.x * 256 + threadIdx.x;
  if (idx >= CC * NN) return;
  const int c = idx / NN;
  const int i = idx - c * NN;
  out[idx] = ce[0] + Q[i * CC + c];
}

extern "C" void kernel_launch(void* const* d_in, const int* in_sizes, int n_in,
                              void* d_out, int out_size, void* d_ws,
                              size_t ws_size, hipStream_t stream) {
  const float* logits = (const float*)d_in[0];
  const int* labels = (const int*)d_in[1];
  const float* image = (const float*)d_in[2];
  float* ws = (float*)d_ws;

  float* U = ws;
  float* Qa = ws + NN * CC;
  float* Qb = ws + 2 * NN * CC;
  float* feats = ws + 3 * NN * CC;
  float* partial = feats + NN * 8;
  float* ce = partial + 64;

  k_setup<<<NBLK, 256, 0, stream>>>(logits, labels, image, U, Qa, feats,
                                    partial);
  k_reduce_ce<<<1, 64, 0, stream>>>(partial, ce);

  const float* qi = Qa;
  float* qo = Qb;
  for (int it = 0; it < 5; ++it) {
    k_mf<<<NBLK, 256, 0, stream>>>(U, qi, feats, qo);
    qi = qo;
    qo = (qo == Qb) ? Qa : Qb;
  }

  k_out<<<(CC * NN + 255) / 256, 256, 0, stream>>>(qi, ce, (float*)d_out);
}

// Round 2
// 430.456 us; speedup vs baseline: 15.0647x; 15.0647x over previous
//
#include <hip/hip_runtime.h>

#define HH 96
#define WW 96
#define CC 21
#define NN (HH*WW)          // 9216
#define NBLK (NN/256)       // 36
#define STRIDE 24           // padded row stride for Q/U/G (16B-aligned rows)
#define RAD 16
#define WIN 33              // 2*RAD+1
#define NPOS (WIN*WIN)      // 1089

// ---------------------------------------------------------------------------
// ws layout (floats):
//   U     [NN*24]   unary, padded
//   Qa    [NN*24]   Q ping
//   Qb    [NN*24]   Q pong
//   Gy    [NN*24]   gauss y-pass intermediate
//   G     [NN*24]   gauss output
//   rgb4  [NN*4]    {r,g,b,0}/255
//   gtab  [96]      exp(-0.5*(d/64)^2)
//   stab  [64]      exp(-0.5*((k-16)/3)^2), k=0..32
//   partial [64], ce [1]
// total ~4.6 MB
// ---------------------------------------------------------------------------

__global__ __launch_bounds__(256) void k_setup(
    const float* __restrict__ logits, const int* __restrict__ labels,
    const float* __restrict__ image, float* __restrict__ U,
    float* __restrict__ Q0, float* __restrict__ rgb4,
    float* __restrict__ gtab, float* __restrict__ stab,
    float* __restrict__ partial) {
  const int t = threadIdx.x;
  const int i = blockIdx.x * 256 + t;

  float d[CC];
  float mx = -1e30f;
#pragma unroll
  for (int c = 0; c < CC; ++c) {
    d[c] = logits[c * NN + i];
    mx = fmaxf(mx, d[c]);
  }
  float s = 0.f;
#pragma unroll
  for (int c = 0; c < CC; ++c) { d[c] -= mx; s += __expf(d[c]); }
  const float lse = logf(s);
  const float inv = 1.f / s;
  const int lab = labels[i];
  float myU = 0.f;
#pragma unroll
  for (int c = 0; c < CC; ++c) {
    const float Uc = lse - d[c];              // -logp
    U[i * STRIDE + c] = Uc;
    Q0[i * STRIDE + c] = __expf(d[c]) * inv;  // softmax
    myU = (c == lab) ? Uc : myU;
  }
#pragma unroll
  for (int c = CC; c < STRIDE; ++c) {
    U[i * STRIDE + c] = 0.f;
    Q0[i * STRIDE + c] = 0.f;
  }

  float4 rv;
  rv.x = image[i] * (1.f / 255.f);
  rv.y = image[NN + i] * (1.f / 255.f);
  rv.z = image[2 * NN + i] * (1.f / 255.f);
  rv.w = 0.f;
  ((float4*)rgb4)[i] = rv;

  if (blockIdx.x == 0) {
    if (t < 96) {
      const float dv = (float)t * (1.f / 64.f);
      gtab[t] = __expf(-0.5f * dv * dv);
    } else if (t < 96 + WIN) {
      const float dv = (float)(t - 96 - RAD) * (1.f / 3.f);
      stab[t - 96] = __expf(-0.5f * dv * dv);
    }
  }

  __shared__ float red[256];
  red[t] = myU;
  __syncthreads();
  for (int off = 128; off > 0; off >>= 1) {
    if (t < off) red[t] += red[t + off];
    __syncthreads();
  }
  if (t == 0) partial[blockIdx.x] = red[0];
}

__global__ void k_reduce_ce(const float* __restrict__ partial,
                            float* __restrict__ ce) {
  float v = (threadIdx.x < NBLK) ? partial[threadIdx.x] : 0.f;
#pragma unroll
  for (int off = 32; off > 0; off >>= 1) v += __shfl_down(v, off);
  if (threadIdx.x == 0) ce[0] = v * (1.f / (float)NN);
}

// separable long-range gaussian, y pass: Gy[(y,x),c] = sum_y' g[|y-y'|] Q[(y',x),c]
__global__ __launch_bounds__(256) void k_gauss_y(
    const float* __restrict__ Qin, float* __restrict__ Gy,
    const float* __restrict__ gtab) {
  __shared__ float g[96];
  if (threadIdx.x < 96) g[threadIdx.x] = gtab[threadIdx.x];
  __syncthreads();
  const int idx = blockIdx.x * 256 + threadIdx.x;   // < NN*STRIDE
  const int c = idx % STRIDE;
  const int i = idx / STRIDE;
  const int y = i / WW, x = i - y * WW;
  const float* col = Qin + x * STRIDE + c;          // + y'*WW*STRIDE
  float acc = 0.f;
#pragma unroll 8
  for (int yp = 0; yp < HH; ++yp) {
    const int ad = (y >= yp) ? (y - yp) : (yp - y);
    acc = fmaf(g[ad], col[yp * (WW * STRIDE)], acc);
  }
  Gy[idx] = acc;
}

// x pass: G[(y,x),c] = sum_x' g[|x-x'|] Gy[(y,x'),c]
__global__ __launch_bounds__(256) void k_gauss_x(
    const float* __restrict__ Gy, float* __restrict__ G,
    const float* __restrict__ gtab) {
  __shared__ float g[96];
  if (threadIdx.x < 96) g[threadIdx.x] = gtab[threadIdx.x];
  __syncthreads();
  const int idx = blockIdx.x * 256 + threadIdx.x;
  const int c = idx % STRIDE;
  const int i = idx / STRIDE;
  const int y = i / WW, x = i - y * WW;
  const float* row = Gy + y * (WW * STRIDE) + c;
  float acc = 0.f;
#pragma unroll 8
  for (int xp = 0; xp < WW; ++xp) {
    const int ad = (x >= xp) ? (x - xp) : (xp - x);
    acc = fmaf(g[ad], row[xp * STRIDE], acc);
  }
  G[idx] = acc;
}

// fused: windowed bilateral filter + combine with gauss + mean-field update.
// one 64-lane wave per pixel; lanes stride the 33x33 window.
__global__ __launch_bounds__(256) void k_bilat(
    const float* __restrict__ U, const float* __restrict__ Qin,
    const float* __restrict__ G, const float* __restrict__ rgb4,
    const float* __restrict__ stab, float* __restrict__ Qout) {
  __shared__ float ss[WIN];
  if (threadIdx.x < WIN) ss[threadIdx.x] = stab[threadIdx.x];
  __syncthreads();

  const int lane = threadIdx.x & 63;
  const int wid = threadIdx.x >> 6;
  const int i = blockIdx.x * 4 + wid;
  const int y = i / WW, x = i - y * WW;

  const float4 ri = ((const float4*)rgb4)[i];

  float msg[CC];
#pragma unroll
  for (int c = 0; c < CC; ++c) msg[c] = 0.f;

#pragma unroll
  for (int k = 0; k < 18; ++k) {
    const int p = lane + (k << 6);
    if (p < NPOS) {
      const int dyi = p / WIN;          // 0..32
      const int dxi = p - dyi * WIN;
      const int yy = y + dyi - RAD;
      const int xx = x + dxi - RAD;
      if ((unsigned)yy < HH && (unsigned)xx < WW) {
        const int j = yy * WW + xx;
        const float4 rj = ((const float4*)rgb4)[j];
        const float dr = rj.x - ri.x, dg = rj.y - ri.y, db = rj.z - ri.z;
        const float w =
            ss[dyi] * ss[dxi] * __expf(-0.5f * (dr * dr + dg * dg + db * db));
        const float4* Qj = (const float4*)(Qin + j * STRIDE);
        float qq[STRIDE];
        *(float4*)(qq + 0) = Qj[0];
        *(float4*)(qq + 4) = Qj[1];
        *(float4*)(qq + 8) = Qj[2];
        *(float4*)(qq + 12) = Qj[3];
        *(float4*)(qq + 16) = Qj[4];
        *(float4*)(qq + 20) = Qj[5];
#pragma unroll
        for (int c = 0; c < CC; ++c) msg[c] = fmaf(w, qq[c], msg[c]);
      }
    }
  }

  // butterfly reduce across the wave: every lane ends with full window sums
#pragma unroll
  for (int off = 32; off >= 1; off >>= 1) {
#pragma unroll
    for (int c = 0; c < CC; ++c) msg[c] += __shfl_xor(msg[c], off, 64);
  }

  // lane c handles class c (static-index select, rule #20)
  float mc = msg[0];
#pragma unroll
  for (int c = 1; c < CC; ++c) mc = (lane == c) ? msg[c] : mc;

  const bool act = lane < CC;
  float Uc = 0.f, Qic = 0.f, Gc = 0.f;
  if (act) {
    Uc = U[i * STRIDE + lane];
    Qic = Qin[i * STRIDE + lane];
    Gc = G[i * STRIDE + lane];
  }
  const float contrib = act ? (mc + Gc - 2.f * Qic) : 0.f;  // self removed
  float tot = contrib;
#pragma unroll
  for (int off = 16; off >= 1; off >>= 1) tot += __shfl_xor(tot, off, 32);
  const float lc = act ? (-Uc - 10.f * (tot - contrib)) : -1e30f;
  float mxl = lc;
#pragma unroll
  for (int off = 16; off >= 1; off >>= 1)
    mxl = fmaxf(mxl, __shfl_xor(mxl, off, 32));
  const float e = act ? __expf(lc - mxl) : 0.f;
  float se = e;
#pragma unroll
  for (int off = 16; off >= 1; off >>= 1) se += __shfl_xor(se, off, 32);
  if (lane < STRIDE) Qout[i * STRIDE + lane] = act ? (e / se) : 0.f;
}

__global__ __launch_bounds__(256) void k_out(
    const float* __restrict__ Q, const float* __restrict__ ce,
    float* __restrict__ out) {
  const int idx = blockIdx.x * 256 + threadIdx.x;
  if (idx >= CC * NN) return;
  const int c = idx / NN;
  const int i = idx - c * NN;
  out[idx] = ce[0] + Q[i * STRIDE + c];
}

extern "C" void kernel_launch(void* const* d_in, const int* in_sizes, int n_in,
                              void* d_out, int out_size, void* d_ws,
                              size_t ws_size, hipStream_t stream) {
  const float* logits = (const float*)d_in[0];
  const int* labels = (const int*)d_in[1];
  const float* image = (const float*)d_in[2];
  float* ws = (float*)d_ws;

  float* U = ws;
  float* Qa = U + NN * STRIDE;
  float* Qb = Qa + NN * STRIDE;
  float* Gy = Qb + NN * STRIDE;
  float* G = Gy + NN * STRIDE;
  float* rgb4 = G + NN * STRIDE;
  float* gtab = rgb4 + NN * 4;
  float* stab = gtab + 96;
  float* partial = stab + 64;
  float* ce = partial + 64;

  k_setup<<<NBLK, 256, 0, stream>>>(logits, labels, image, U, Qa, rgb4, gtab,
                                    stab, partial);
  k_reduce_ce<<<1, 64, 0, stream>>>(partial, ce);

  const float* qi = Qa;
  float* qo = Qb;
  const int gblk = NN * STRIDE / 256;  // 864
  for (int it = 0; it < 5; ++it) {
    k_gauss_y<<<gblk, 256, 0, stream>>>(qi, Gy, gtab);
    k_gauss_x<<<gblk, 256, 0, stream>>>(Gy, G, gtab);
    k_bilat<<<NN / 4, 256, 0, stream>>>(U, qi, G, rgb4, stab, qo);
    qi = qo;
    qo = (qo == Qb) ? Qa : Qb;
  }

  k_out<<<(CC * NN + 255) / 256, 256, 0, stream>>>(qi, ce, (float*)d_out);
}

// Round 4
// 353.896 us; speedup vs baseline: 18.3237x; 1.2163x over previous
//
#include <hip/hip_runtime.h>

#define HH 96
#define WW 96
#define CC 21
#define NN (HH*WW)          // 9216
#define NBLK (NN/256)       // 36
#define STRIDE 24           // padded row stride for Q/U/G
#define ROWF (WW*STRIDE)    // 2304 floats per image row

// ---------------------------------------------------------------------------
// ws layout (floats): U[NN*24] Qa[NN*24] Qb[NN*24] Gy[NN*24] G[NN*24]
//                     rgb4[NN*4] gtab[96] partial[64] ce[1]
// ---------------------------------------------------------------------------

__global__ __launch_bounds__(256) void k_setup(
    const float* __restrict__ logits, const int* __restrict__ labels,
    const float* __restrict__ image, float* __restrict__ U,
    float* __restrict__ Q0, float* __restrict__ rgb4,
    float* __restrict__ gtab, float* __restrict__ partial) {
  const int t = threadIdx.x;
  const int i = blockIdx.x * 256 + t;

  float d[CC];
  float mx = -1e30f;
#pragma unroll
  for (int c = 0; c < CC; ++c) {
    d[c] = logits[c * NN + i];
    mx = fmaxf(mx, d[c]);
  }
  float s = 0.f;
#pragma unroll
  for (int c = 0; c < CC; ++c) { d[c] -= mx; s += __expf(d[c]); }
  const float lse = logf(s);
  const float inv = 1.f / s;
  const int lab = labels[i];
  float myU = 0.f;
#pragma unroll
  for (int c = 0; c < CC; ++c) {
    const float Uc = lse - d[c];              // -logp
    U[i * STRIDE + c] = Uc;
    Q0[i * STRIDE + c] = __expf(d[c]) * inv;  // softmax
    myU = (c == lab) ? Uc : myU;
  }
#pragma unroll
  for (int c = CC; c < STRIDE; ++c) {
    U[i * STRIDE + c] = 0.f;
    Q0[i * STRIDE + c] = 0.f;
  }

  float4 rv;
  rv.x = image[i] * (1.f / 255.f);
  rv.y = image[NN + i] * (1.f / 255.f);
  rv.z = image[2 * NN + i] * (1.f / 255.f);
  rv.w = 0.f;
  ((float4*)rgb4)[i] = rv;

  if (blockIdx.x == 0 && t < 96) {
    const float dv = (float)t * (1.f / 64.f);
    gtab[t] = __expf(-0.5f * dv * dv);
  }

  __shared__ float red[256];
  red[t] = myU;
  __syncthreads();
  for (int off = 128; off > 0; off >>= 1) {
    if (t < off) red[t] += red[t + off];
    __syncthreads();
  }
  if (t == 0) partial[blockIdx.x] = red[0];
}

__global__ void k_reduce_ce(const float* __restrict__ partial,
                            float* __restrict__ ce) {
  float v = (threadIdx.x < NBLK) ? partial[threadIdx.x] : 0.f;
#pragma unroll
  for (int off = 32; off > 0; off >>= 1) v += __shfl_down(v, off);
  if (threadIdx.x == 0) ce[0] = v * (1.f / (float)NN);
}

// separable long-range gaussian, 4 outputs per thread.
__global__ __launch_bounds__(256) void k_gauss_y(
    const float* __restrict__ Qin, float* __restrict__ Gy,
    const float* __restrict__ gtab) {
  __shared__ float g[96];
  if (threadIdx.x < 96) g[threadIdx.x] = gtab[threadIdx.x];
  __syncthreads();
  const int q = blockIdx.x * 256 + threadIdx.x;  // 55296 quads
  const int ygrp = q / ROWF;                     // 0..23 (ROWF=2304)
  const int rem = q - ygrp * ROWF;               // x*24+c
  const int y0 = ygrp * 4;
  float a0 = 0.f, a1 = 0.f, a2 = 0.f, a3 = 0.f;
  const float* base = Qin + rem;
#pragma unroll 4
  for (int yp = 0; yp < HH; ++yp) {
    const float v = base[yp * ROWF];
    const int d = y0 - yp;
    a0 = fmaf(g[abs(d)], v, a0);
    a1 = fmaf(g[abs(d + 1)], v, a1);
    a2 = fmaf(g[abs(d + 2)], v, a2);
    a3 = fmaf(g[abs(d + 3)], v, a3);
  }
  float* ob = Gy + rem;
  ob[(y0 + 0) * ROWF] = a0;
  ob[(y0 + 1) * ROWF] = a1;
  ob[(y0 + 2) * ROWF] = a2;
  ob[(y0 + 3) * ROWF] = a3;
}

__global__ __launch_bounds__(256) void k_gauss_x(
    const float* __restrict__ Gy, float* __restrict__ G,
    const float* __restrict__ gtab) {
  __shared__ float g[96];
  if (threadIdx.x < 96) g[threadIdx.x] = gtab[threadIdx.x];
  __syncthreads();
  const int q = blockIdx.x * 256 + threadIdx.x;
  const int y = q / 576;                 // 24 xgrp * 24 c
  const int rem = q - y * 576;
  const int xgrp = rem / 24, c = rem - xgrp * 24;
  const int x0 = xgrp * 4;
  float a0 = 0.f, a1 = 0.f, a2 = 0.f, a3 = 0.f;
  const float* base = Gy + y * ROWF + c;
#pragma unroll 4
  for (int xp = 0; xp < WW; ++xp) {
    const float v = base[xp * STRIDE];
    const int d = x0 - xp;
    a0 = fmaf(g[abs(d)], v, a0);
    a1 = fmaf(g[abs(d + 1)], v, a1);
    a2 = fmaf(g[abs(d + 2)], v, a2);
    a3 = fmaf(g[abs(d + 3)], v, a3);
  }
  float* ob = G + y * ROWF + c;
  ob[(x0 + 0) * STRIDE] = a0;
  ob[(x0 + 1) * STRIDE] = a1;
  ob[(x0 + 2) * STRIDE] = a2;
  ob[(x0 + 3) * STRIDE] = a3;
}

// ---------------------------------------------------------------------------
// windowed bilateral, tile-gather form.
// block = 4 waves = one 4x4 pixel tile. lane = (grp, px): grp = j-slice,
// px = pixel. Union window = 36x36 = 1296 absolute j's; iter t covers
// j's [16t, 16t+16): wave w, group g handles jj = 16t + 4w + g, broadcast
// to its 16 pixel-lanes. 81 iters, 2-stage software pipeline.
// ---------------------------------------------------------------------------
struct JBuf {
  float4 q0, q1, q2, q3, q4, q5, rj;
  float fy, fx;
  int ok;
};

__device__ __forceinline__ void loadj(JBuf& b, int t, int wg, int grp,
                                      int ty0, int tx0, int pr, int pc,
                                      const float* __restrict__ Qin,
                                      const float* __restrict__ rgb4) {
  const int jj = t * 16 + (wg << 2) + grp;
  const int ry = jj / 36, rx = jj - ry * 36;
  const int yj = ty0 - 16 + ry, xj = tx0 - 16 + rx;
  b.ok = ((unsigned)(ry - pr) <= 32u) & ((unsigned)(rx - pc) <= 32u) &
         ((unsigned)yj < (unsigned)HH) & ((unsigned)xj < (unsigned)WW);
  const int yc = min(max(yj, 0), HH - 1);
  const int xc = min(max(xj, 0), WW - 1);
  const int j = yc * WW + xc;
  const float4* qp = (const float4*)(Qin + j * STRIDE);
  b.q0 = qp[0]; b.q1 = qp[1]; b.q2 = qp[2];
  b.q3 = qp[3]; b.q4 = qp[4]; b.q5 = qp[5];
  b.rj = ((const float4*)rgb4)[j];
  b.fy = (float)yj;
  b.fx = (float)xj;
}

__device__ __forceinline__ void accum(const JBuf& b, const float4 ri,
                                      float fyi, float fxi, float* msg) {
  const float dy = b.fy - fyi, dx = b.fx - fxi;
  const float dr = b.rj.x - ri.x, dg = b.rj.y - ri.y, db = b.rj.z - ri.z;
  const float d2s = dy * dy + dx * dx;
  const float d2c = dr * dr + dg * dg + db * db;
  // exponent = -0.5*(d2s/9) - 0.5*d2c  (spatial sigma 3, color pre-scaled)
  float wgt = __expf(fmaf(d2s, -0.5f / 9.f, -0.5f * d2c));
  wgt = b.ok ? wgt : 0.f;
  msg[0]  = fmaf(wgt, b.q0.x, msg[0]);
  msg[1]  = fmaf(wgt, b.q0.y, msg[1]);
  msg[2]  = fmaf(wgt, b.q0.z, msg[2]);
  msg[3]  = fmaf(wgt, b.q0.w, msg[3]);
  msg[4]  = fmaf(wgt, b.q1.x, msg[4]);
  msg[5]  = fmaf(wgt, b.q1.y, msg[5]);
  msg[6]  = fmaf(wgt, b.q1.z, msg[6]);
  msg[7]  = fmaf(wgt, b.q1.w, msg[7]);
  msg[8]  = fmaf(wgt, b.q2.x, msg[8]);
  msg[9]  = fmaf(wgt, b.q2.y, msg[9]);
  msg[10] = fmaf(wgt, b.q2.z, msg[10]);
  msg[11] = fmaf(wgt, b.q2.w, msg[11]);
  msg[12] = fmaf(wgt, b.q3.x, msg[12]);
  msg[13] = fmaf(wgt, b.q3.y, msg[13]);
  msg[14] = fmaf(wgt, b.q3.z, msg[14]);
  msg[15] = fmaf(wgt, b.q3.w, msg[15]);
  msg[16] = fmaf(wgt, b.q4.x, msg[16]);
  msg[17] = fmaf(wgt, b.q4.y, msg[17]);
  msg[18] = fmaf(wgt, b.q4.z, msg[18]);
  msg[19] = fmaf(wgt, b.q4.w, msg[19]);
  msg[20] = fmaf(wgt, b.q5.x, msg[20]);
}

__global__ __launch_bounds__(256) void k_bilat(
    const float* __restrict__ U, const float* __restrict__ Qin,
    const float* __restrict__ G, const float* __restrict__ rgb4,
    float* __restrict__ Qout) {
  __shared__ float sm[4][16][21];
  const int tid = threadIdx.x;
  const int wg = tid >> 6;
  const int lane = tid & 63;
  const int grp = lane >> 4;
  const int px = lane & 15;
  const int pr = px >> 2, pc = px & 3;

  const int tile = blockIdx.x;           // 24x24 tiles
  const int ty0 = (tile / 24) * 4;
  const int tx0 = (tile - (tile / 24) * 24) * 4;
  const int yi = ty0 + pr, xi = tx0 + pc;
  const int i = yi * WW + xi;
  const float fyi = (float)yi, fxi = (float)xi;

  const float4 ri = ((const float4*)rgb4)[i];

  float msg[CC];
#pragma unroll
  for (int c = 0; c < CC; ++c) msg[c] = 0.f;

  JBuf A, B;
  loadj(A, 0, wg, grp, ty0, tx0, pr, pc, Qin, rgb4);
#pragma unroll 4
  for (int t = 0; t < 80; t += 2) {
    loadj(B, t + 1, wg, grp, ty0, tx0, pr, pc, Qin, rgb4);
    accum(A, ri, fyi, fxi, msg);
    loadj(A, t + 2, wg, grp, ty0, tx0, pr, pc, Qin, rgb4);
    accum(B, ri, fyi, fxi, msg);
  }
  accum(A, ri, fyi, fxi, msg);           // t = 80

  // reduce the 4 j-slices within the wave
#pragma unroll
  for (int c = 0; c < CC; ++c) {
    msg[c] += __shfl_xor(msg[c], 16, 64);
    msg[c] += __shfl_xor(msg[c], 32, 64);
  }
  if (lane < 16) {
#pragma unroll
    for (int c = 0; c < CC; ++c) sm[wg][px][c] = msg[c];
  }
  __syncthreads();

  // cross-wave sum + mean-field update; wave wg owns pixels 4wg..4wg+3
  const bool act = lane < CC;
  for (int p = 0; p < 4; ++p) {
    const int pp = (wg << 2) + p;
    const int ip = (ty0 + (pp >> 2)) * WW + tx0 + (pp & 3);
    float tc = 0.f, Uc = 0.f, Qic = 0.f, Gc = 0.f;
    if (act) {
      tc = sm[0][pp][lane] + sm[1][pp][lane] + sm[2][pp][lane] +
           sm[3][pp][lane];
      Uc = U[ip * STRIDE + lane];
      Qic = Qin[ip * STRIDE + lane];
      Gc = G[ip * STRIDE + lane];
    }
    const float contrib = act ? (tc + Gc - 2.f * Qic) : 0.f;  // self removed
    float tot = contrib;
#pragma unroll
    for (int off = 16; off >= 1; off >>= 1) tot += __shfl_xor(tot, off, 32);
    const float lc = act ? (-Uc - 10.f * (tot - contrib)) : -1e30f;
    float mxl = lc;
#pragma unroll
    for (int off = 16; off >= 1; off >>= 1)
      mxl = fmaxf(mxl, __shfl_xor(mxl, off, 32));
    const float e = act ? __expf(lc - mxl) : 0.f;
    float se = e;
#pragma unroll
    for (int off = 16; off >= 1; off >>= 1) se += __shfl_xor(se, off, 32);
    if (lane < STRIDE) Qout[ip * STRIDE + lane] = act ? (e / se) : 0.f;
  }
}

__global__ __launch_bounds__(256) void k_out(
    const float* __restrict__ Q, const float* __restrict__ ce,
    float* __restrict__ out) {
  const int idx = blockIdx.x * 256 + threadIdx.x;
  if (idx >= CC * NN) return;
  const int c = idx / NN;
  const int i = idx - c * NN;
  out[idx] = ce[0] + Q[i * STRIDE + c];
}

extern "C" void kernel_launch(void* const* d_in, const int* in_sizes, int n_in,
                              void* d_out, int out_size, void* d_ws,
                              size_t ws_size, hipStream_t stream) {
  const float* logits = (const float*)d_in[0];
  const int* labels = (const int*)d_in[1];
  const float* image = (const float*)d_in[2];
  float* ws = (float*)d_ws;

  float* U = ws;
  float* Qa = U + NN * STRIDE;
  float* Qb = Qa + NN * STRIDE;
  float* Gy = Qb + NN * STRIDE;
  float* G = Gy + NN * STRIDE;
  float* rgb4 = G + NN * STRIDE;
  float* gtab = rgb4 + NN * 4;
  float* partial = gtab + 96;
  float* ce = partial + 64;

  k_setup<<<NBLK, 256, 0, stream>>>(logits, labels, image, U, Qa, rgb4, gtab,
                                    partial);
  k_reduce_ce<<<1, 64, 0, stream>>>(partial, ce);

  const float* qi = Qa;
  float* qo = Qb;
  const int gblk = NN * STRIDE / (256 * 4);  // 216
  for (int it = 0; it < 5; ++it) {
    k_gauss_y<<<gblk, 256, 0, stream>>>(qi, Gy, gtab);
    k_gauss_x<<<gblk, 256, 0, stream>>>(Gy, G, gtab);
    k_bilat<<<576, 256, 0, stream>>>(U, qi, G, rgb4, qo);
    qi = qo;
    qo = (qo == Qb) ? Qa : Qb;
  }

  k_out<<<(CC * NN + 255) / 256, 256, 0, stream>>>(qi, ce, (float*)d_out);
}

// Round 5
// 267.465 us; speedup vs baseline: 24.2450x; 1.3231x over previous
//
#include <hip/hip_runtime.h>

#define HH 96
#define WW 96
#define CC 21
#define NN (HH*WW)          // 9216
#define NBLK (NN/256)       // 36
#define STRIDE 24           // 21 classes + r,g,b packed in padding
#define ROWF (WW*STRIDE)    // 2304 floats per image row

// ---------------------------------------------------------------------------
// ws layout (floats): U[NN*24] Qa[NN*24] Qb[NN*24] Gy[NN*24] G[NN*24]
//                     gtab[96] partial[64] ce[1]
// Q rows: [0..20] = class probs, [21..23] = rgb/255 (propagated every iter).
// ---------------------------------------------------------------------------

__global__ __launch_bounds__(256) void k_setup(
    const float* __restrict__ logits, const int* __restrict__ labels,
    const float* __restrict__ image, float* __restrict__ U,
    float* __restrict__ Q0, float* __restrict__ gtab,
    float* __restrict__ partial) {
  const int t = threadIdx.x;
  const int i = blockIdx.x * 256 + t;

  float d[CC];
  float mx = -1e30f;
#pragma unroll
  for (int c = 0; c < CC; ++c) {
    d[c] = logits[c * NN + i];
    mx = fmaxf(mx, d[c]);
  }
  float s = 0.f;
#pragma unroll
  for (int c = 0; c < CC; ++c) { d[c] -= mx; s += __expf(d[c]); }
  const float lse = logf(s);
  const float inv = 1.f / s;
  const int lab = labels[i];
  float myU = 0.f;
#pragma unroll
  for (int c = 0; c < CC; ++c) {
    const float Uc = lse - d[c];              // -logp
    U[i * STRIDE + c] = Uc;
    Q0[i * STRIDE + c] = __expf(d[c]) * inv;  // softmax
    myU = (c == lab) ? Uc : myU;
  }
  U[i * STRIDE + 21] = 0.f;
  U[i * STRIDE + 22] = 0.f;
  U[i * STRIDE + 23] = 0.f;
  // rgb in the Q padding
  Q0[i * STRIDE + 21] = image[i] * (1.f / 255.f);
  Q0[i * STRIDE + 22] = image[NN + i] * (1.f / 255.f);
  Q0[i * STRIDE + 23] = image[2 * NN + i] * (1.f / 255.f);

  if (blockIdx.x == 0 && t < 96) {
    const float dv = (float)t * (1.f / 64.f);
    gtab[t] = __expf(-0.5f * dv * dv);
  }

  __shared__ float red[256];
  red[t] = myU;
  __syncthreads();
  for (int off = 128; off > 0; off >>= 1) {
    if (t < off) red[t] += red[t + off];
    __syncthreads();
  }
  if (t == 0) partial[blockIdx.x] = red[0];
}

__global__ void k_reduce_ce(const float* __restrict__ partial,
                            float* __restrict__ ce) {
  float v = (threadIdx.x < NBLK) ? partial[threadIdx.x] : 0.f;
#pragma unroll
  for (int off = 32; off > 0; off >>= 1) v += __shfl_down(v, off);
  if (threadIdx.x == 0) ce[0] = v * (1.f / (float)NN);
}

// separable long-range gaussian (sigma 64), 1 output/thread, 864 blocks.
__global__ __launch_bounds__(256) void k_gauss_y(
    const float* __restrict__ Qin, float* __restrict__ Gy,
    const float* __restrict__ gtab) {
  __shared__ float g[96];
  if (threadIdx.x < 96) g[threadIdx.x] = gtab[threadIdx.x];
  __syncthreads();
  const int idx = blockIdx.x * 256 + threadIdx.x;  // < NN*STRIDE
  const int y = idx / ROWF;                        // block-uniform
  const int rem = idx - y * ROWF;
  const float* base = Qin + rem;
  float acc = 0.f;
#pragma unroll 8
  for (int yp = 0; yp < HH; ++yp)
    acc = fmaf(g[abs(y - yp)], base[yp * ROWF], acc);
  Gy[idx] = acc;
}

__global__ __launch_bounds__(256) void k_gauss_x(
    const float* __restrict__ Gy, float* __restrict__ G,
    const float* __restrict__ gtab) {
  __shared__ float g[96];
  if (threadIdx.x < 96) g[threadIdx.x] = gtab[threadIdx.x];
  __syncthreads();
  const int idx = blockIdx.x * 256 + threadIdx.x;
  const int y = idx / ROWF;
  const int rem = idx - y * ROWF;
  const int x = rem / STRIDE;
  const int c = rem - x * STRIDE;
  const float* base = Gy + y * ROWF + c;           // lane-varying c only
  float acc = 0.f;
#pragma unroll 8
  for (int xp = 0; xp < WW; ++xp)
    acc = fmaf(g[abs(x - xp)], base[xp * STRIDE], acc);
  G[idx] = acc;
}

// ---------------------------------------------------------------------------
// windowed bilateral, 4x2 pixel tiles. block = 4 waves; lane = (grp, px):
// grp = lane>>3 in 0..7 (j-slice), px = lane&7 (pixel: pr=px>>1, pc=px&1).
// Union window 36x34 = 1224 positions; per iter t the block's 32 lane-groups
// cover jj in [32t, 32t+32). 39 iters, 2-stage pipeline, 6 float4 loads/j.
// ---------------------------------------------------------------------------
struct JBuf {
  float4 q0, q1, q2, q3, q4, q5;   // 21 classes + rgb in q5.yzw
  float d2s;
  int ok;
};

__device__ __forceinline__ void loadj(JBuf& b, int t, int wg, int grp,
                                      int ty0, int tx0, int pr, int pc,
                                      const float* __restrict__ Qin) {
  const int jj = (t << 5) + (wg << 3) + grp;   // < 1248
  const int ry = jj / 34, rx = jj - ry * 34;   // ry 0..36, rx 0..33
  const int dyi = ry - pr, dxi = rx - pc;      // must be in [0,32]
  const int yj = ty0 - 16 + ry, xj = tx0 - 16 + rx;
  b.ok = ((unsigned)dyi <= 32u) & ((unsigned)dxi <= 32u) &
         ((unsigned)yj < (unsigned)HH) & ((unsigned)xj < (unsigned)WW);
  const int yc = min(max(yj, 0), HH - 1);
  const int xc = min(max(xj, 0), WW - 1);
  const float4* qp = (const float4*)(Qin + (yc * WW + xc) * STRIDE);
  b.q0 = qp[0]; b.q1 = qp[1]; b.q2 = qp[2];
  b.q3 = qp[3]; b.q4 = qp[4]; b.q5 = qp[5];
  const int dy = dyi - 16, dx = dxi - 16;
  b.d2s = (float)(dy * dy + dx * dx);
}

__device__ __forceinline__ void accum(const JBuf& b, float rr, float rg,
                                      float rb, float* msg) {
  const float dr = b.q5.y - rr, dg = b.q5.z - rg, db = b.q5.w - rb;
  const float d2c = fmaf(dr, dr, fmaf(dg, dg, db * db));
  // exponent = -0.5*(d2s/9 + d2c): spatial sigma 3, color pre-scaled by 255
  float wgt = __expf(fmaf(b.d2s, -1.f / 18.f, -0.5f * d2c));
  wgt = b.ok ? wgt : 0.f;
  msg[0]  = fmaf(wgt, b.q0.x, msg[0]);
  msg[1]  = fmaf(wgt, b.q0.y, msg[1]);
  msg[2]  = fmaf(wgt, b.q0.z, msg[2]);
  msg[3]  = fmaf(wgt, b.q0.w, msg[3]);
  msg[4]  = fmaf(wgt, b.q1.x, msg[4]);
  msg[5]  = fmaf(wgt, b.q1.y, msg[5]);
  msg[6]  = fmaf(wgt, b.q1.z, msg[6]);
  msg[7]  = fmaf(wgt, b.q1.w, msg[7]);
  msg[8]  = fmaf(wgt, b.q2.x, msg[8]);
  msg[9]  = fmaf(wgt, b.q2.y, msg[9]);
  msg[10] = fmaf(wgt, b.q2.z, msg[10]);
  msg[11] = fmaf(wgt, b.q2.w, msg[11]);
  msg[12] = fmaf(wgt, b.q3.x, msg[12]);
  msg[13] = fmaf(wgt, b.q3.y, msg[13]);
  msg[14] = fmaf(wgt, b.q3.z, msg[14]);
  msg[15] = fmaf(wgt, b.q3.w, msg[15]);
  msg[16] = fmaf(wgt, b.q4.x, msg[16]);
  msg[17] = fmaf(wgt, b.q4.y, msg[17]);
  msg[18] = fmaf(wgt, b.q4.z, msg[18]);
  msg[19] = fmaf(wgt, b.q4.w, msg[19]);
  msg[20] = fmaf(wgt, b.q5.x, msg[20]);
}

__global__ __launch_bounds__(256) void k_bilat(
    const float* __restrict__ U, const float* __restrict__ Qin,
    const float* __restrict__ G, float* __restrict__ Qout) {
  __shared__ float sm[4][8][21];
  const int tid = threadIdx.x;
  const int wg = tid >> 6;
  const int lane = tid & 63;
  const int grp = lane >> 3;           // 0..7
  const int px = lane & 7;             // 0..7
  const int pr = px >> 1, pc = px & 1;

  const int tile = blockIdx.x;         // 24 rows x 48 cols of 4x2 tiles
  const int tr = tile / 48;
  const int tc = tile - tr * 48;
  const int ty0 = tr * 4, tx0 = tc * 2;
  const int i = (ty0 + pr) * WW + (tx0 + pc);

  // own pixel rgb from the Q-row padding
  const float4 rown = *(const float4*)(Qin + i * STRIDE + 20);
  const float rr = rown.y, rg = rown.z, rb = rown.w;

  float msg[CC];
#pragma unroll
  for (int c = 0; c < CC; ++c) msg[c] = 0.f;

  JBuf A, B;
  loadj(A, 0, wg, grp, ty0, tx0, pr, pc, Qin);
#pragma unroll 1
  for (int t = 0; t < 38; t += 2) {
    loadj(B, t + 1, wg, grp, ty0, tx0, pr, pc, Qin);
    accum(A, rr, rg, rb, msg);
    loadj(A, t + 2, wg, grp, ty0, tx0, pr, pc, Qin);
    accum(B, rr, rg, rb, msg);
  }
  accum(A, rr, rg, rb, msg);           // iter 38

  // reduce the 8 j-slices within the wave (grp bits are lane bits 3..5)
#pragma unroll
  for (int c = 0; c < CC; ++c) {
    msg[c] += __shfl_xor(msg[c], 8, 64);
    msg[c] += __shfl_xor(msg[c], 16, 64);
    msg[c] += __shfl_xor(msg[c], 32, 64);
  }
  if (lane < 8) {
#pragma unroll
    for (int c = 0; c < CC; ++c) sm[wg][px][c] = msg[c];
  }
  __syncthreads();

  // cross-wave sum + mean-field update; wave wg owns pixels 2wg, 2wg+1
  const bool act = lane < CC;
  for (int p = 0; p < 2; ++p) {
    const int pp = (wg << 1) + p;
    const int ip = (ty0 + (pp >> 1)) * WW + tx0 + (pp & 1);
    float tcv = 0.f, Uc = 0.f, Gc = 0.f;
    float Qic = 0.f;
    if (lane < STRIDE) Qic = Qin[ip * STRIDE + lane];  // 21..23 = rgb
    if (act) {
      tcv = sm[0][pp][lane] + sm[1][pp][lane] + sm[2][pp][lane] +
            sm[3][pp][lane];
      Uc = U[ip * STRIDE + lane];
      Gc = G[ip * STRIDE + lane];
    }
    const float contrib = act ? (tcv + Gc - 2.f * Qic) : 0.f;  // self removed
    float tot = contrib;
#pragma unroll
    for (int off = 16; off >= 1; off >>= 1) tot += __shfl_xor(tot, off, 32);
    const float lc = act ? (-Uc - 10.f * (tot - contrib)) : -1e30f;
    float mxl = lc;
#pragma unroll
    for (int off = 16; off >= 1; off >>= 1)
      mxl = fmaxf(mxl, __shfl_xor(mxl, off, 32));
    const float e = act ? __expf(lc - mxl) : 0.f;
    float se = e;
#pragma unroll
    for (int off = 16; off >= 1; off >>= 1) se += __shfl_xor(se, off, 32);
    if (lane < STRIDE) Qout[ip * STRIDE + lane] = act ? (e / se) : Qic;
  }
}

__global__ __launch_bounds__(256) void k_out(
    const float* __restrict__ Q, const float* __restrict__ ce,
    float* __restrict__ out) {
  const int idx = blockIdx.x * 256 + threadIdx.x;
  if (idx >= CC * NN) return;
  const int c = idx / NN;
  const int i = idx - c * NN;
  out[idx] = ce[0] + Q[i * STRIDE + c];
}

extern "C" void kernel_launch(void* const* d_in, const int* in_sizes, int n_in,
                              void* d_out, int out_size, void* d_ws,
                              size_t ws_size, hipStream_t stream) {
  const float* logits = (const float*)d_in[0];
  const int* labels = (const int*)d_in[1];
  const float* image = (const float*)d_in[2];
  float* ws = (float*)d_ws;

  float* U = ws;
  float* Qa = U + NN * STRIDE;
  float* Qb = Qa + NN * STRIDE;
  float* Gy = Qb + NN * STRIDE;
  float* G = Gy + NN * STRIDE;
  float* gtab = G + NN * STRIDE;
  float* partial = gtab + 96;
  float* ce = partial + 64;

  k_setup<<<NBLK, 256, 0, stream>>>(logits, labels, image, U, Qa, gtab,
                                    partial);
  k_reduce_ce<<<1, 64, 0, stream>>>(partial, ce);

  const float* qi = Qa;
  float* qo = Qb;
  const int gblk = NN * STRIDE / 256;  // 864
  for (int it = 0; it < 5; ++it) {
    k_gauss_y<<<gblk, 256, 0, stream>>>(qi, Gy, gtab);
    k_gauss_x<<<gblk, 256, 0, stream>>>(Gy, G, gtab);
    k_bilat<<<1152, 256, 0, stream>>>(U, qi, G, qo);
    qi = qo;
    qo = (qo == Qb) ? Qa : Qb;
  }

  k_out<<<(CC * NN + 255) / 256, 256, 0, stream>>>(qi, ce, (float*)d_out);
}

// Round 6
// 156.750 us; speedup vs baseline: 41.3696x; 1.7063x over previous
//
#include <hip/hip_runtime.h>
#include <hip/hip_fp16.h>

#define HH 96
#define WW 96
#define CC 21
#define NN (HH*WW)          // 9216
#define NBLK (NN/256)       // 36
#define STRIDE 24           // 21 classes + r,g,b packed in padding
#define ROWF (WW*STRIDE)    // 2304 floats per image row
#define QTROWS 24           // f16 transposed Q: rows 0..20 classes, 21..23 rgb

typedef _Float16 f16x8 __attribute__((ext_vector_type(8)));
typedef float f32x4 __attribute__((ext_vector_type(4)));

union H8 { f16x8 v; __half2 h2[4]; };

// ---------------------------------------------------------------------------
// ws layout (floats):
//   U[NN*24] Qa[NN*24] Qb[NN*24] Gy[NN*24] G[NN*24]   (5 x 221184)
//   gtab[96] partial[64] ce[64]
//   QTa[24*9216 f16 = 110592 floats]  QTb[same]
// Q rows: [0..20] probs, [21..23] rgb/255. QT rows: same, class-major.
// ---------------------------------------------------------------------------

__global__ __launch_bounds__(256) void k_setup(
    const float* __restrict__ logits, const int* __restrict__ labels,
    const float* __restrict__ image, float* __restrict__ U,
    float* __restrict__ Q0, _Float16* __restrict__ QTa,
    _Float16* __restrict__ QTb, float* __restrict__ gtab,
    float* __restrict__ partial) {
  const int t = threadIdx.x;
  const int i = blockIdx.x * 256 + t;

  float d[CC];
  float mx = -1e30f;
#pragma unroll
  for (int c = 0; c < CC; ++c) {
    d[c] = logits[c * NN + i];
    mx = fmaxf(mx, d[c]);
  }
  float s = 0.f;
#pragma unroll
  for (int c = 0; c < CC; ++c) { d[c] -= mx; s += __expf(d[c]); }
  const float lse = logf(s);
  const float inv = 1.f / s;
  const int lab = labels[i];
  float myU = 0.f;
#pragma unroll
  for (int c = 0; c < CC; ++c) {
    const float Uc = lse - d[c];              // -logp
    const float q = __expf(d[c]) * inv;       // softmax
    U[i * STRIDE + c] = Uc;
    Q0[i * STRIDE + c] = q;
    QTa[c * NN + i] = (_Float16)q;
    myU = (c == lab) ? Uc : myU;
  }
  const float rr = image[i] * (1.f / 255.f);
  const float rg = image[NN + i] * (1.f / 255.f);
  const float rb = image[2 * NN + i] * (1.f / 255.f);
  U[i * STRIDE + 21] = 0.f;
  U[i * STRIDE + 22] = 0.f;
  U[i * STRIDE + 23] = 0.f;
  Q0[i * STRIDE + 21] = rr;
  Q0[i * STRIDE + 22] = rg;
  Q0[i * STRIDE + 23] = rb;
  // rgb rows are static: write into BOTH QT buffers
  QTa[21 * NN + i] = (_Float16)rr;
  QTa[22 * NN + i] = (_Float16)rg;
  QTa[23 * NN + i] = (_Float16)rb;
  QTb[21 * NN + i] = (_Float16)rr;
  QTb[22 * NN + i] = (_Float16)rg;
  QTb[23 * NN + i] = (_Float16)rb;

  if (blockIdx.x == 0 && t < 96) {
    const float dv = (float)t * (1.f / 64.f);
    gtab[t] = __expf(-0.5f * dv * dv);
  }

  __shared__ float red[256];
  red[t] = myU;
  __syncthreads();
  for (int off = 128; off > 0; off >>= 1) {
    if (t < off) red[t] += red[t + off];
    __syncthreads();
  }
  if (t == 0) partial[blockIdx.x] = red[0];
}

// separable long-range gaussian (sigma 64), 1 output/thread, 864 blocks.
__global__ __launch_bounds__(256) void k_gauss_y(
    const float* __restrict__ Qin, float* __restrict__ Gy,
    const float* __restrict__ gtab) {
  __shared__ float g[96];
  if (threadIdx.x < 96) g[threadIdx.x] = gtab[threadIdx.x];
  __syncthreads();
  const int idx = blockIdx.x * 256 + threadIdx.x;  // < NN*STRIDE
  const int y = idx / ROWF;                        // block-uniform
  const int rem = idx - y * ROWF;
  const float* base = Qin + rem;
  float acc = 0.f;
#pragma unroll 8
  for (int yp = 0; yp < HH; ++yp)
    acc = fmaf(g[abs(y - yp)], base[yp * ROWF], acc);
  Gy[idx] = acc;
}

__global__ __launch_bounds__(256) void k_gauss_x(
    const float* __restrict__ Gy, float* __restrict__ G,
    const float* __restrict__ gtab) {
  __shared__ float g[96];
  if (threadIdx.x < 96) g[threadIdx.x] = gtab[threadIdx.x];
  __syncthreads();
  const int idx = blockIdx.x * 256 + threadIdx.x;
  const int y = idx / ROWF;
  const int rem = idx - y * ROWF;
  const int x = rem / STRIDE;
  const int c = rem - x * STRIDE;
  const float* base = Gy + y * ROWF + c;           // lane-varying c only
  float acc = 0.f;
#pragma unroll 8
  for (int xp = 0; xp < WW; ++xp)
    acc = fmaf(g[abs(x - xp)], base[xp * STRIDE], acc);
  G[idx] = acc;
}

// ---------------------------------------------------------------------------
// MFMA bilateral + mean-field update.
// block = 512 thr = 8 waves = one 4x4 pixel tile.
// Union window rows: 36 (yj in [ty0-16, ty0+19]), split: waves 0-3 get 5
// rows, waves 4-7 get 4. Each row = 5 absolute-8-aligned x-runs of 8.
// K-chunk = 4 runs = 32 j's -> 1 A-fragment (weights, computed in half2)
// and 2 B-fragments (QT rows 0-15, 16-23) -> 2 MFMA 16x16x32 f16.
// A lane l: pixel = l&15, run-in-chunk = l>>4, 8 j's = A elements.
// D lane l: class col = l&15, pixel rows = (l>>4)*4 + reg.
// ---------------------------------------------------------------------------
__global__ __launch_bounds__(512) void k_bilat(
    const float* __restrict__ U, const float* __restrict__ Qin,
    const float* __restrict__ G, const _Float16* __restrict__ QT,
    float* __restrict__ Qout, _Float16* __restrict__ QTout) {
  __shared__ __half sytab[64];
  __shared__ __half2 sxtab[64];
  __shared__ float psum[8][16][24];

  const int tid = threadIdx.x;
  const int w = tid >> 6;        // wave 0..7
  const int l = tid & 63;
  const int g = l >> 4;          // run-in-chunk / D-row-group
  const int q = l & 15;          // A: pixel; B/D: class col

  if (tid < 64) {
    const float dv = (float)(tid - 32);
    sytab[tid] = __float2half(__expf(dv * dv * (-1.f / 18.f)));
    const float dv1 = dv + 1.f;
    sxtab[tid] = __floats2half2_rn(__expf(dv * dv * (-1.f / 18.f)),
                                   __expf(dv1 * dv1 * (-1.f / 18.f)));
  }
  __syncthreads();

  const int tile = blockIdx.x;   // 24x24 tiles
  const int ty0 = (tile / 24) * 4;
  const int tx0 = (tile - (tile / 24) * 24) * 4;

  // this lane's pixel (A-row)
  const int pr = q >> 2, pc = q & 3;
  const int yi = ty0 + pr, xi = tx0 + pc;
  const int ipix = yi * WW + xi;

  // own rgb (from f32 Q padding), broadcast to half2
  const float4 rown = *(const float4*)(Qin + ipix * STRIDE + 20);
  const __half2 ri_r = __float2half2_rn(rown.y);
  const __half2 ri_g = __float2half2_rn(rown.z);
  const __half2 ri_b = __float2half2_rn(rown.w);
  const __half2 mhalf = __floats2half2_rn(-0.5f, -0.5f);
  const __half hzero = __float2half(0.f);

  const int xs = tx0 - 16;
  const int xbase0 = (xs > 0 ? xs : 0) & ~7;
  const int rows0 = (w < 4) ? w * 5 : 20 + (w - 4) * 4;
  const int nrun = ((w < 4) ? 5 : 4) * 5;
  const int nck = (nrun + 3) >> 2;   // 7 or 5

  const int brow2 = (16 + q > 23) ? 23 : 16 + q;   // clamped B2 row

  f32x4 acc0 = {0.f, 0.f, 0.f, 0.f};
  f32x4 acc1 = {0.f, 0.f, 0.f, 0.f};

#pragma unroll 2
  for (int ck = 0; ck < 7; ++ck) {
    if (ck >= nck) break;
    const int r = ck * 4 + g;              // run id within wave
    const int wr = r / 5;
    const int cs = r - wr * 5;
    const int yj = ty0 - 16 + rows0 + wr;
    const int xb = xbase0 + cs * 8;
    const bool ok = (r < nrun) & (yj >= 0) & (yj < HH) & (xb <= WW - 8);
    const int yc = min(max(yj, 0), HH - 1);
    const int xc = min(xb, WW - 8);
    const int jb = yc * WW + xc;

    H8 b1, b2, rj, gj, bj;
    b1.v = *(const f16x8*)(QT + q * NN + jb);
    b2.v = *(const f16x8*)(QT + brow2 * NN + jb);
    rj.v = *(const f16x8*)(QT + 21 * NN + jb);
    gj.v = *(const f16x8*)(QT + 22 * NN + jb);
    bj.v = *(const f16x8*)(QT + 23 * NN + jb);

    const int dy = yj - yi;
    const int iy = min(max(dy + 32, 0), 63);
    const __half syv = ok ? sytab[iy] : hzero;
    const __half2 sy2 = __half2half2(syv);
    const int dx0 = xb - xi;
    const int ix0 = min(max(dx0 + 32, 0), 57);

    H8 af;
#pragma unroll
    for (int e2 = 0; e2 < 4; ++e2) {
      const __half2 sx2 = sxtab[ix0 + 2 * e2];
      const __half2 dr = __hsub2(rj.h2[e2], ri_r);
      const __half2 dg = __hsub2(gj.h2[e2], ri_g);
      const __half2 db = __hsub2(bj.h2[e2], ri_b);
      __half2 d2c = __hmul2(dr, dr);
      d2c = __hfma2(dg, dg, d2c);
      d2c = __hfma2(db, db, d2c);
      const __half2 ec = h2exp(__hmul2(d2c, mhalf));
      af.h2[e2] = __hmul2(__hmul2(sy2, sx2), ec);
    }
    acc0 = __builtin_amdgcn_mfma_f32_16x16x32_f16(af.v, b1.v, acc0, 0, 0, 0);
    acc1 = __builtin_amdgcn_mfma_f32_16x16x32_f16(af.v, b2.v, acc1, 0, 0, 0);
  }

  // stage partials: lane l holds D rows g*4+reg, col q (acc0) / 16+q (acc1)
#pragma unroll
  for (int reg = 0; reg < 4; ++reg) {
    psum[w][g * 4 + reg][q] = acc0[reg];
    if (q < 8) psum[w][g * 4 + reg][16 + q] = acc1[reg];
  }
  __syncthreads();

  // mean-field update: wave w owns pixels 2w, 2w+1 (one per 32-half)
  const int half_ = l >> 5;
  const int cl = l & 31;
  const bool act = cl < CC;
  const int pix = w * 2 + half_;
  const int ip = (ty0 + (pix >> 2)) * WW + tx0 + (pix & 3);
  float Qic = 0.f;
  if (cl < STRIDE) Qic = Qin[ip * STRIDE + cl];
  float tcv = 0.f, Uc = 0.f, Gc = 0.f;
  if (act) {
    tcv = psum[0][pix][cl] + psum[1][pix][cl] + psum[2][pix][cl] +
          psum[3][pix][cl] + psum[4][pix][cl] + psum[5][pix][cl] +
          psum[6][pix][cl] + psum[7][pix][cl];
    Uc = U[ip * STRIDE + cl];
    Gc = G[ip * STRIDE + cl];
  }
  const float contrib = act ? (tcv + Gc - 2.f * Qic) : 0.f;  // self removed
  float tot = contrib;
#pragma unroll
  for (int off = 16; off >= 1; off >>= 1) tot += __shfl_xor(tot, off, 32);
  const float lc = act ? (-Uc - 10.f * (tot - contrib)) : -1e30f;
  float mxl = lc;
#pragma unroll
  for (int off = 16; off >= 1; off >>= 1)
    mxl = fmaxf(mxl, __shfl_xor(mxl, off, 32));
  const float e = act ? __expf(lc - mxl) : 0.f;
  float se = e;
#pragma unroll
  for (int off = 16; off >= 1; off >>= 1) se += __shfl_xor(se, off, 32);
  const float qnew = e / se;
  if (cl < STRIDE) Qout[ip * STRIDE + cl] = act ? qnew : Qic;
  if (act) QTout[cl * NN + ip] = (_Float16)qnew;
}

// output + CE reduction folded in (reads 36 per-block partials)
__global__ __launch_bounds__(256) void k_out(
    const float* __restrict__ Q, const float* __restrict__ partial,
    float* __restrict__ out) {
  __shared__ float ces;
  if (threadIdx.x < 64) {
    float v = (threadIdx.x < NBLK) ? partial[threadIdx.x] : 0.f;
#pragma unroll
    for (int off = 32; off > 0; off >>= 1) v += __shfl_down(v, off);
    if (threadIdx.x == 0) ces = v * (1.f / (float)NN);
  }
  __syncthreads();
  const int idx = blockIdx.x * 256 + threadIdx.x;
  if (idx >= CC * NN) return;
  const int c = idx / NN;
  const int i = idx - c * NN;
  out[idx] = ces + Q[i * STRIDE + c];
}

extern "C" void kernel_launch(void* const* d_in, const int* in_sizes, int n_in,
                              void* d_out, int out_size, void* d_ws,
                              size_t ws_size, hipStream_t stream) {
  const float* logits = (const float*)d_in[0];
  const int* labels = (const int*)d_in[1];
  const float* image = (const float*)d_in[2];
  float* ws = (float*)d_ws;

  float* U = ws;
  float* Qa = U + NN * STRIDE;
  float* Qb = Qa + NN * STRIDE;
  float* Gy = Qb + NN * STRIDE;
  float* G = Gy + NN * STRIDE;
  float* gtab = G + NN * STRIDE;
  float* partial = gtab + 96;
  float* cepad = partial + 64;
  _Float16* QTa = (_Float16*)(cepad + 64);
  _Float16* QTb = QTa + QTROWS * NN;

  k_setup<<<NBLK, 256, 0, stream>>>(logits, labels, image, U, Qa, QTa, QTb,
                                    gtab, partial);

  const float* qi = Qa;
  float* qo = Qb;
  const _Float16* qti = QTa;
  _Float16* qto = QTb;
  const int gblk = NN * STRIDE / 256;  // 864
  for (int it = 0; it < 5; ++it) {
    k_gauss_y<<<gblk, 256, 0, stream>>>(qi, Gy, gtab);
    k_gauss_x<<<gblk, 256, 0, stream>>>(Gy, G, gtab);
    k_bilat<<<576, 512, 0, stream>>>(U, qi, G, qti, qo, qto);
    qi = qo;
    qo = (qo == Qb) ? Qa : Qb;
    const _Float16* tmp = qti;
    qti = qto;
    qto = (_Float16*)tmp;
  }

  k_out<<<(CC * NN + 255) / 256, 256, 0, stream>>>(qi, partial, (float*)d_out);
}

// Round 7
// 142.559 us; speedup vs baseline: 45.4878x; 1.0995x over previous
//
#include <hip/hip_runtime.h>
#include <hip/hip_fp16.h>

#define HH 96
#define WW 96
#define CC 21
#define NN (HH*WW)          // 9216
#define NBLK (NN/256)       // 36
#define STRIDE 24           // 21 classes + r,g,b packed in padding
#define ROWF (WW*STRIDE)    // 2304 floats per image row
#define NRUN (NN/8)         // 1152 8-pixel runs
// QT2 layout: [jrun][24 classes][8 px] f16, 384 B per run-block.

typedef _Float16 f16x8 __attribute__((ext_vector_type(8)));
typedef float f32x4 __attribute__((ext_vector_type(4)));

union H8 { f16x8 v; __half2 h2[4]; };

// ---------------------------------------------------------------------------
// ws layout (floats):
//   U[NN*24] Qa[NN*24] Qb[NN*24] Gy[NN*24]
//   gtab[96] partial[64] ce[64]
//   QT2a[NRUN*192 f16] QT2b[same]
// ---------------------------------------------------------------------------

__global__ __launch_bounds__(256) void k_setup(
    const float* __restrict__ logits, const int* __restrict__ labels,
    const float* __restrict__ image, float* __restrict__ U,
    float* __restrict__ Q0, _Float16* __restrict__ QTa,
    _Float16* __restrict__ QTb, float* __restrict__ gtab,
    float* __restrict__ partial) {
  const int t = threadIdx.x;
  const int i = blockIdx.x * 256 + t;
  const int qoff = (i >> 3) * 192 + (i & 7);   // QT2 slot for class 0

  float d[CC];
  float mx = -1e30f;
#pragma unroll
  for (int c = 0; c < CC; ++c) {
    d[c] = logits[c * NN + i];
    mx = fmaxf(mx, d[c]);
  }
  float s = 0.f;
#pragma unroll
  for (int c = 0; c < CC; ++c) { d[c] -= mx; s += __expf(d[c]); }
  const float lse = logf(s);
  const float inv = 1.f / s;
  const int lab = labels[i];
  float myU = 0.f;
#pragma unroll
  for (int c = 0; c < CC; ++c) {
    const float Uc = lse - d[c];              // -logp
    const float q = __expf(d[c]) * inv;       // softmax
    U[i * STRIDE + c] = Uc;
    Q0[i * STRIDE + c] = q;
    QTa[qoff + c * 8] = (_Float16)q;
    myU = (c == lab) ? Uc : myU;
  }
  const float rr = image[i] * (1.f / 255.f);
  const float rg = image[NN + i] * (1.f / 255.f);
  const float rb = image[2 * NN + i] * (1.f / 255.f);
  U[i * STRIDE + 21] = 0.f;
  U[i * STRIDE + 22] = 0.f;
  U[i * STRIDE + 23] = 0.f;
  Q0[i * STRIDE + 21] = rr;
  Q0[i * STRIDE + 22] = rg;
  Q0[i * STRIDE + 23] = rb;
  // rgb rows are static: write into BOTH QT2 buffers
  QTa[qoff + 21 * 8] = (_Float16)rr;
  QTa[qoff + 22 * 8] = (_Float16)rg;
  QTa[qoff + 23 * 8] = (_Float16)rb;
  QTb[qoff + 21 * 8] = (_Float16)rr;
  QTb[qoff + 22 * 8] = (_Float16)rg;
  QTb[qoff + 23 * 8] = (_Float16)rb;

  if (blockIdx.x == 0 && t < 96) {
    const float dv = (float)t * (1.f / 64.f);
    gtab[t] = __expf(-0.5f * dv * dv);
  }

  __shared__ float red[256];
  red[t] = myU;
  __syncthreads();
  for (int off = 128; off > 0; off >>= 1) {
    if (t < off) red[t] += red[t + off];
    __syncthreads();
  }
  if (t == 0) partial[blockIdx.x] = red[0];
}

// separable long-range gaussian (sigma 64), y pass, 864 blocks.
__global__ __launch_bounds__(256) void k_gauss_y(
    const float* __restrict__ Qin, float* __restrict__ Gy,
    const float* __restrict__ gtab) {
  __shared__ float g[96];
  if (threadIdx.x < 96) g[threadIdx.x] = gtab[threadIdx.x];
  __syncthreads();
  const int idx = blockIdx.x * 256 + threadIdx.x;  // < NN*STRIDE
  const int y = idx / ROWF;                        // block-uniform
  const int rem = idx - y * ROWF;
  const float* base = Qin + rem;
  float acc = 0.f;
#pragma unroll 8
  for (int yp = 0; yp < HH; ++yp)
    acc = fmaf(g[abs(y - yp)], base[yp * ROWF], acc);
  Gy[idx] = acc;
}

// ---------------------------------------------------------------------------
// MFMA bilateral + fused gauss-x + mean-field update.
// block = 512 thr = 8 waves = one 4x4 pixel tile.
// Window rows 36 split across waves (5/4); each row = 5 8-aligned x-runs.
// K-chunk = 4 runs = 32 j -> A = weights (half2 chain), B from QT2 blocked
// layout: all 5 loads of a g-group hit the same 384B run-block (6 lines).
// ---------------------------------------------------------------------------
__global__ __launch_bounds__(512) void k_bilat(
    const float* __restrict__ U, const float* __restrict__ Qin,
    const float* __restrict__ Gy, const _Float16* __restrict__ QT,
    const float* __restrict__ gtab, float* __restrict__ Qout,
    _Float16* __restrict__ QTout) {
  __shared__ __half sytab[64];
  __shared__ __half2 sxtab[64];
  __shared__ float sgt[96];
  __shared__ float psum[8][16][24];

  const int tid = threadIdx.x;
  const int w = tid >> 6;        // wave 0..7
  const int l = tid & 63;
  const int g = l >> 4;          // run-in-chunk / D-row-group
  const int q = l & 15;          // A: pixel; B/D: class col

  if (tid < 64) {
    const float dv = (float)(tid - 32);
    sytab[tid] = __float2half(__expf(dv * dv * (-1.f / 18.f)));
    const float dv1 = dv + 1.f;
    sxtab[tid] = __floats2half2_rn(__expf(dv * dv * (-1.f / 18.f)),
                                   __expf(dv1 * dv1 * (-1.f / 18.f)));
  } else if (tid < 160) {
    sgt[tid - 64] = gtab[tid - 64];
  }
  __syncthreads();

  const int tile = blockIdx.x;   // 24x24 tiles
  const int ty0 = (tile / 24) * 4;
  const int tx0 = (tile - (tile / 24) * 24) * 4;

  // this lane's pixel (A-row)
  const int pr = q >> 2, pc = q & 3;
  const int yi = ty0 + pr, xi = tx0 + pc;
  const int ipix = yi * WW + xi;

  // own rgb (from f32 Q padding), broadcast to half2
  const float4 rown = *(const float4*)(Qin + ipix * STRIDE + 20);
  const __half2 ri_r = __float2half2_rn(rown.y);
  const __half2 ri_g = __float2half2_rn(rown.z);
  const __half2 ri_b = __float2half2_rn(rown.w);
  const __half2 mhalf = __floats2half2_rn(-0.5f, -0.5f);
  const __half hzero = __float2half(0.f);

  const int xs = tx0 - 16;
  const int xbase0 = (xs > 0 ? xs : 0) & ~7;
  const int rows0 = (w < 4) ? w * 5 : 20 + (w - 4) * 4;
  const int nrun = ((w < 4) ? 5 : 4) * 5;
  const int nck = (nrun + 3) >> 2;   // 7 or 5

  const int row2 = (16 + q > 23) ? 23 : 16 + q;   // clamped B2 row

  f32x4 acc0 = {0.f, 0.f, 0.f, 0.f};
  f32x4 acc1 = {0.f, 0.f, 0.f, 0.f};

#pragma unroll 2
  for (int ck = 0; ck < 7; ++ck) {
    if (ck >= nck) break;
    const int r = ck * 4 + g;              // run id within wave
    const int wr = r / 5;
    const int cs = r - wr * 5;
    const int yj = ty0 - 16 + rows0 + wr;
    const int xb = xbase0 + cs * 8;
    const bool ok = (r < nrun) & (yj >= 0) & (yj < HH) & (xb <= WW - 8);
    const int yc = min(max(yj, 0), HH - 1);
    const int xc = min(xb, WW - 8);
    const _Float16* base = QT + (yc * 12 + (xc >> 3)) * 192;

    H8 b1, b2, rj, gj, bj;
    b1.v = *(const f16x8*)(base + q * 8);
    b2.v = *(const f16x8*)(base + row2 * 8);
    rj.v = *(const f16x8*)(base + 21 * 8);
    gj.v = *(const f16x8*)(base + 22 * 8);
    bj.v = *(const f16x8*)(base + 23 * 8);

    const int dy = yj - yi;
    const int iy = min(max(dy + 32, 0), 63);
    const __half syv = ok ? sytab[iy] : hzero;
    const __half2 sy2 = __half2half2(syv);
    const int dx0 = xb - xi;
    const int ix0 = min(max(dx0 + 32, 0), 57);

    H8 af;
#pragma unroll
    for (int e2 = 0; e2 < 4; ++e2) {
      const __half2 sx2 = sxtab[ix0 + 2 * e2];
      const __half2 dr = __hsub2(rj.h2[e2], ri_r);
      const __half2 dg = __hsub2(gj.h2[e2], ri_g);
      const __half2 db = __hsub2(bj.h2[e2], ri_b);
      __half2 d2c = __hmul2(dr, dr);
      d2c = __hfma2(dg, dg, d2c);
      d2c = __hfma2(db, db, d2c);
      const __half2 ec = h2exp(__hmul2(d2c, mhalf));
      af.h2[e2] = __hmul2(__hmul2(sy2, sx2), ec);
    }
    acc0 = __builtin_amdgcn_mfma_f32_16x16x32_f16(af.v, b1.v, acc0, 0, 0, 0);
    acc1 = __builtin_amdgcn_mfma_f32_16x16x32_f16(af.v, b2.v, acc1, 0, 0, 0);
  }

  // stage partials: lane l holds D rows g*4+reg, col q (acc0) / 16+q (acc1)
#pragma unroll
  for (int reg = 0; reg < 4; ++reg) {
    psum[w][g * 4 + reg][q] = acc0[reg];
    if (q < 8) psum[w][g * 4 + reg][16 + q] = acc1[reg];
  }
  __syncthreads();

  // mean-field update: wave w owns pixels 2w, 2w+1 (one per 32-half)
  const int half_ = l >> 5;
  const int cl = l & 31;
  const bool act = cl < CC;
  const int pix = w * 2 + half_;
  const int py = ty0 + (pix >> 2), px = tx0 + (pix & 3);
  const int ip = py * WW + px;
  float Qic = 0.f;
  if (cl < STRIDE) Qic = Qin[ip * STRIDE + cl];
  float tcv = 0.f, Uc = 0.f, Gc = 0.f;
  if (act) {
    tcv = psum[0][pix][cl] + psum[1][pix][cl] + psum[2][pix][cl] +
          psum[3][pix][cl] + psum[4][pix][cl] + psum[5][pix][cl] +
          psum[6][pix][cl] + psum[7][pix][cl];
    Uc = U[ip * STRIDE + cl];
    // fused gauss-x: G[ip][cl] = sum_xp g[|px-xp|] * Gy[py][xp][cl]
    const float* grow = Gy + py * ROWF + cl;
#pragma unroll 8
    for (int xp = 0; xp < WW; ++xp)
      Gc = fmaf(sgt[abs(px - xp)], grow[xp * STRIDE], Gc);
  }
  const float contrib = act ? (tcv + Gc - 2.f * Qic) : 0.f;  // self removed
  float tot = contrib;
#pragma unroll
  for (int off = 16; off >= 1; off >>= 1) tot += __shfl_xor(tot, off, 32);
  const float lc = act ? (-Uc - 10.f * (tot - contrib)) : -1e30f;
  float mxl = lc;
#pragma unroll
  for (int off = 16; off >= 1; off >>= 1)
    mxl = fmaxf(mxl, __shfl_xor(mxl, off, 32));
  const float e = act ? __expf(lc - mxl) : 0.f;
  float se = e;
#pragma unroll
  for (int off = 16; off >= 1; off >>= 1) se += __shfl_xor(se, off, 32);
  const float qnew = e / se;
  if (cl < STRIDE) Qout[ip * STRIDE + cl] = act ? qnew : Qic;
  if (act) QTout[(ip >> 3) * 192 + cl * 8 + (ip & 7)] = (_Float16)qnew;
}

// output + CE reduction folded in (reads 36 per-block partials)
__global__ __launch_bounds__(256) void k_out(
    const float* __restrict__ Q, const float* __restrict__ partial,
    float* __restrict__ out) {
  __shared__ float ces;
  if (threadIdx.x < 64) {
    float v = (threadIdx.x < NBLK) ? partial[threadIdx.x] : 0.f;
#pragma unroll
    for (int off = 32; off > 0; off >>= 1) v += __shfl_down(v, off);
    if (threadIdx.x == 0) ces = v * (1.f / (float)NN);
  }
  __syncthreads();
  const int idx = blockIdx.x * 256 + threadIdx.x;
  if (idx >= CC * NN) return;
  const int c = idx / NN;
  const int i = idx - c * NN;
  out[idx] = ces + Q[i * STRIDE + c];
}

extern "C" void kernel_launch(void* const* d_in, const int* in_sizes, int n_in,
                              void* d_out, int out_size, void* d_ws,
                              size_t ws_size, hipStream_t stream) {
  const float* logits = (const float*)d_in[0];
  const int* labels = (const int*)d_in[1];
  const float* image = (const float*)d_in[2];
  float* ws = (float*)d_ws;

  float* U = ws;
  float* Qa = U + NN * STRIDE;
  float* Qb = Qa + NN * STRIDE;
  float* Gy = Qb + NN * STRIDE;
  float* gtab = Gy + NN * STRIDE;
  float* partial = gtab + 96;
  float* cepad = partial + 64;
  _Float16* QTa = (_Float16*)(cepad + 64);
  _Float16* QTb = QTa + NRUN * 192;

  k_setup<<<NBLK, 256, 0, stream>>>(logits, labels, image, U, Qa, QTa, QTb,
                                    gtab, partial);

  const float* qi = Qa;
  float* qo = Qb;
  const _Float16* qti = QTa;
  _Float16* qto = QTb;
  const int gblk = NN * STRIDE / 256;  // 864
  for (int it = 0; it < 5; ++it) {
    k_gauss_y<<<gblk, 256, 0, stream>>>(qi, Gy, gtab);
    k_bilat<<<576, 512, 0, stream>>>(U, qi, Gy, qti, gtab, qo, qto);
    qi = qo;
    qo = (qo == Qb) ? Qa : Qb;
    const _Float16* tmp = qti;
    qti = qto;
    qto = (_Float16*)tmp;
  }

  k_out<<<(CC * NN + 255) / 256, 256, 0, stream>>>(qi, partial, (float*)d_out);
}

// Round 9
// 138.237 us; speedup vs baseline: 46.9098x; 1.0313x over previous
//
#include <hip/hip_runtime.h>
#include <hip/hip_fp16.h>

#define HH 96
#define WW 96
#define CC 21
#define NN (HH*WW)          // 9216
#define NBLK (NN/256)       // 36
#define STRIDE 24           // 21 classes + r,g,b packed in padding
#define ROWF (WW*STRIDE)    // 2304 floats per image row
#define NRUN (NN/8)         // 1152 8-pixel runs
// QT2 layout: [jrun][24 classes][8 px] f16, 384 B per run-block.

typedef _Float16 f16x8 __attribute__((ext_vector_type(8)));
typedef float f32x4 __attribute__((ext_vector_type(4)));

union H8 { f16x8 v; __half2 h2[4]; };

// ---------------------------------------------------------------------------
// ws layout (floats):
//   U[NN*24] Qa[NN*24] Qb[NN*24] Gy[NN*24]
//   gtab[96] partial[64] ce[64]
//   QT2a[NRUN*192 f16] QT2b[same]
// ---------------------------------------------------------------------------

__global__ __launch_bounds__(256) void k_setup(
    const float* __restrict__ logits, const int* __restrict__ labels,
    const float* __restrict__ image, float* __restrict__ U,
    float* __restrict__ Q0, _Float16* __restrict__ QTa,
    _Float16* __restrict__ QTb, float* __restrict__ gtab,
    float* __restrict__ partial) {
  const int t = threadIdx.x;
  const int i = blockIdx.x * 256 + t;
  const int qoff = (i >> 3) * 192 + (i & 7);   // QT2 slot for class 0

  float d[CC];
  float mx = -1e30f;
#pragma unroll
  for (int c = 0; c < CC; ++c) {
    d[c] = logits[c * NN + i];
    mx = fmaxf(mx, d[c]);
  }
  float s = 0.f;
#pragma unroll
  for (int c = 0; c < CC; ++c) { d[c] -= mx; s += __expf(d[c]); }
  const float lse = logf(s);
  const float inv = 1.f / s;
  const int lab = labels[i];
  float myU = 0.f;
#pragma unroll
  for (int c = 0; c < CC; ++c) {
    const float Uc = lse - d[c];              // -logp
    const float q = __expf(d[c]) * inv;       // softmax
    U[i * STRIDE + c] = Uc;
    Q0[i * STRIDE + c] = q;
    QTa[qoff + c * 8] = (_Float16)q;
    myU = (c == lab) ? Uc : myU;
  }
  const float rr = image[i] * (1.f / 255.f);
  const float rg = image[NN + i] * (1.f / 255.f);
  const float rb = image[2 * NN + i] * (1.f / 255.f);
  U[i * STRIDE + 21] = 0.f;
  U[i * STRIDE + 22] = 0.f;
  U[i * STRIDE + 23] = 0.f;
  Q0[i * STRIDE + 21] = rr;
  Q0[i * STRIDE + 22] = rg;
  Q0[i * STRIDE + 23] = rb;
  // rgb rows are static: write into BOTH QT2 buffers
  QTa[qoff + 21 * 8] = (_Float16)rr;
  QTa[qoff + 22 * 8] = (_Float16)rg;
  QTa[qoff + 23 * 8] = (_Float16)rb;
  QTb[qoff + 21 * 8] = (_Float16)rr;
  QTb[qoff + 22 * 8] = (_Float16)rg;
  QTb[qoff + 23 * 8] = (_Float16)rb;

  if (blockIdx.x == 0 && t < 96) {
    const float dv = (float)t * (1.f / 64.f);
    gtab[t] = __expf(-0.5f * dv * dv);
  }

  __shared__ float red[256];
  red[t] = myU;
  __syncthreads();
  for (int off = 128; off > 0; off >>= 1) {
    if (t < off) red[t] += red[t + off];
    __syncthreads();
  }
  if (t == 0) partial[blockIdx.x] = red[0];
}

// separable long-range gaussian (sigma 64), y pass, 864 blocks.
__global__ __launch_bounds__(256) void k_gauss_y(
    const float* __restrict__ Qin, float* __restrict__ Gy,
    const float* __restrict__ gtab) {
  __shared__ float g[96];
  if (threadIdx.x < 96) g[threadIdx.x] = gtab[threadIdx.x];
  __syncthreads();
  const int idx = blockIdx.x * 256 + threadIdx.x;  // < NN*STRIDE
  const int y = idx / ROWF;                        // block-uniform
  const int rem = idx - y * ROWF;
  const float* base = Qin + rem;
  float a0 = 0.f, a1 = 0.f, a2 = 0.f, a3 = 0.f;
#pragma unroll 6
  for (int yp = 0; yp < HH; yp += 4) {
    a0 = fmaf(g[abs(y - yp)], base[yp * ROWF], a0);
    a1 = fmaf(g[abs(y - yp - 1)], base[(yp + 1) * ROWF], a1);
    a2 = fmaf(g[abs(y - yp - 2)], base[(yp + 2) * ROWF], a2);
    a3 = fmaf(g[abs(y - yp - 3)], base[(yp + 3) * ROWF], a3);
  }
  Gy[idx] = (a0 + a1) + (a2 + a3);
}

// ---------------------------------------------------------------------------
// MFMA bilateral + fused gauss-x + mean-field update (+ final output).
// block = 512 thr = 8 waves = one 4x4 pixel tile.
// 180 window runs (36 rows x 5 8-aligned x-runs) split 23/23/23/23/22/22/22/22
// across waves -> 6 uniform K-chunks of 4 runs (32 j) for every wave.
// Fully unrolled: loads from all chunks can be in flight together.
// ---------------------------------------------------------------------------
__global__ __launch_bounds__(512) void k_bilat(
    const float* __restrict__ U, const float* __restrict__ Qin,
    const float* __restrict__ Gy, const _Float16* __restrict__ QT,
    const float* __restrict__ gtab, float* __restrict__ Qout,
    _Float16* __restrict__ QTout, const float* __restrict__ partial,
    float* __restrict__ out, int last) {
  __shared__ __half sytab[64];
  __shared__ __half2 sxtab[64];
  __shared__ float sgt[96];
  __shared__ float psum[8][16][24];
  __shared__ float sces;

  const int tid = threadIdx.x;
  const int w = tid >> 6;        // wave 0..7
  const int l = tid & 63;
  const int g = l >> 4;          // run-in-chunk / D-row-group
  const int q = l & 15;          // A: pixel; B/D: class col

  if (tid < 64) {
    const float dv = (float)(tid - 32);
    sytab[tid] = __float2half(__expf(dv * dv * (-1.f / 18.f)));
    const float dv1 = dv + 1.f;
    sxtab[tid] = __floats2half2_rn(__expf(dv * dv * (-1.f / 18.f)),
                                   __expf(dv1 * dv1 * (-1.f / 18.f)));
    if (last) {
      float v = (tid < NBLK) ? partial[tid] : 0.f;
#pragma unroll
      for (int off = 32; off >= 1; off >>= 1) v += __shfl_xor(v, off, 64);
      if (tid == 0) sces = v * (1.f / (float)NN);
    }
  } else if (tid < 160) {
    sgt[tid - 64] = gtab[tid - 64];
  }
  __syncthreads();

  const int tile = blockIdx.x;   // 24x24 tiles
  const int ty0 = (tile / 24) * 4;
  const int tx0 = (tile - (tile / 24) * 24) * 4;

  // this lane's pixel (A-row)
  const int pr = q >> 2, pc = q & 3;
  const int yi = ty0 + pr, xi = tx0 + pc;
  const int ipix = yi * WW + xi;

  // own rgb (from f32 Q padding), broadcast to half2
  const float4 rown = *(const float4*)(Qin + ipix * STRIDE + 20);
  const __half2 ri_r = __float2half2_rn(rown.y);
  const __half2 ri_g = __float2half2_rn(rown.z);
  const __half2 ri_b = __float2half2_rn(rown.w);
  const __half2 mhalf = __floats2half2_rn(-0.5f, -0.5f);
  const __half hzero = __float2half(0.f);

  const int xs = tx0 - 16;
  const int xbase0 = (xs > 0 ? xs : 0) & ~7;
  // even 23/22 run split: waves 0-3 -> 23 runs, waves 4-7 -> 22 runs
  const int rid0 = (w < 4) ? w * 23 : 92 + (w - 4) * 22;
  const int nrun = (w < 4) ? 23 : 22;

  const int row2 = (16 + q > 23) ? 23 : 16 + q;   // clamped B2 row

  f32x4 acc0 = {0.f, 0.f, 0.f, 0.f};
  f32x4 acc1 = {0.f, 0.f, 0.f, 0.f};

#pragma unroll
  for (int ck = 0; ck < 6; ++ck) {
    const int r = ck * 4 + g;              // run-in-wave (dummy if >= nrun)
    const int rid = rid0 + r;              // global run id, < 182
    const int wr = rid / 5;                // window row 0..36
    const int cs = rid - wr * 5;           // x-run 0..4
    const int yj = ty0 - 16 + wr;
    const int xb = xbase0 + cs * 8;
    const bool ok = (r < nrun) & (yj >= 0) & (yj < HH) & (xb <= WW - 8);
    const int yc = min(max(yj, 0), HH - 1);
    const int xc = min(xb, WW - 8);
    const _Float16* base = QT + (yc * 12 + (xc >> 3)) * 192;

    H8 b1, b2, rj, gj, bj;
    b1.v = *(const f16x8*)(base + q * 8);
    b2.v = *(const f16x8*)(base + row2 * 8);
    rj.v = *(const f16x8*)(base + 21 * 8);
    gj.v = *(const f16x8*)(base + 22 * 8);
    bj.v = *(const f16x8*)(base + 23 * 8);

    const int dy = yj - yi;
    const int iy = min(max(dy + 32, 0), 63);
    const __half syv = ok ? sytab[iy] : hzero;
    const __half2 sy2 = __half2half2(syv);
    const int dx0 = xb - xi;
    const int ix0 = min(max(dx0 + 32, 0), 57);

    H8 af;
#pragma unroll
    for (int e2 = 0; e2 < 4; ++e2) {
      const __half2 sx2 = sxtab[ix0 + 2 * e2];
      const __half2 dr = __hsub2(rj.h2[e2], ri_r);
      const __half2 dg = __hsub2(gj.h2[e2], ri_g);
      const __half2 db = __hsub2(bj.h2[e2], ri_b);
      __half2 d2c = __hmul2(dr, dr);
      d2c = __hfma2(dg, dg, d2c);
      d2c = __hfma2(db, db, d2c);
      const __half2 ec = h2exp(__hmul2(d2c, mhalf));
      af.h2[e2] = __hmul2(__hmul2(sy2, sx2), ec);
    }
    acc0 = __builtin_amdgcn_mfma_f32_16x16x32_f16(af.v, b1.v, acc0, 0, 0, 0);
    acc1 = __builtin_amdgcn_mfma_f32_16x16x32_f16(af.v, b2.v, acc1, 0, 0, 0);
  }

  // stage partials: lane l holds D rows g*4+reg, col q (acc0) / 16+q (acc1)
#pragma unroll
  for (int reg = 0; reg < 4; ++reg) {
    psum[w][g * 4 + reg][q] = acc0[reg];
    if (q < 8) psum[w][g * 4 + reg][16 + q] = acc1[reg];
  }
  __syncthreads();

  // mean-field update: wave w owns pixels 2w, 2w+1 (one per 32-half)
  const int half_ = l >> 5;
  const int cl = l & 31;
  const bool act = cl < CC;
  const int pix = w * 2 + half_;
  const int py = ty0 + (pix >> 2), px = tx0 + (pix & 3);
  const int ip = py * WW + px;
  float Qic = 0.f;
  if (cl < STRIDE) Qic = Qin[ip * STRIDE + cl];
  float tcv = 0.f, Uc = 0.f, Gc = 0.f;
  if (act) {
    tcv = psum[0][pix][cl] + psum[1][pix][cl] + psum[2][pix][cl] +
          psum[3][pix][cl] + psum[4][pix][cl] + psum[5][pix][cl] +
          psum[6][pix][cl] + psum[7][pix][cl];
    Uc = U[ip * STRIDE + cl];
    // fused gauss-x, 4 independent chains
    const float* grow = Gy + py * ROWF + cl;
    float g0 = 0.f, g1 = 0.f, g2 = 0.f, g3 = 0.f;
#pragma unroll 6
    for (int xp = 0; xp < WW; xp += 4) {
      g0 = fmaf(sgt[abs(px - xp)], grow[xp * STRIDE], g0);
      g1 = fmaf(sgt[abs(px - xp - 1)], grow[(xp + 1) * STRIDE], g1);
      g2 = fmaf(sgt[abs(px - xp - 2)], grow[(xp + 2) * STRIDE], g2);
      g3 = fmaf(sgt[abs(px - xp - 3)], grow[(xp + 3) * STRIDE], g3);
    }
    Gc = (g0 + g1) + (g2 + g3);
  }
  const float contrib = act ? (tcv + Gc - 2.f * Qic) : 0.f;  // self removed
  float tot = contrib;
#pragma unroll
  for (int off = 16; off >= 1; off >>= 1) tot += __shfl_xor(tot, off, 32);
  const float lc = act ? (-Uc - 10.f * (tot - contrib)) : -1e30f;
  float mxl = lc;
#pragma unroll
  for (int off = 16; off >= 1; off >>= 1)
    mxl = fmaxf(mxl, __shfl_xor(mxl, off, 32));
  const float e = act ? __expf(lc - mxl) : 0.f;
  float se = e;
#pragma unroll
  for (int off = 16; off >= 1; off >>= 1) se += __shfl_xor(se, off, 32);
  const float qnew = e / se;
  if (last) {
    if (act) out[cl * NN + ip] = sces + qnew;    // final CHW output
  } else {
    if (cl < STRIDE) Qout[ip * STRIDE + cl] = act ? qnew : Qic;
    if (act) QTout[(ip >> 3) * 192 + cl * 8 + (ip & 7)] = (_Float16)qnew;
  }
}

extern "C" void kernel_launch(void* const* d_in, const int* in_sizes, int n_in,
                              void* d_out, int out_size, void* d_ws,
                              size_t ws_size, hipStream_t stream) {
  const float* logits = (const float*)d_in[0];
  const int* labels = (const int*)d_in[1];
  const float* image = (const float*)d_in[2];
  float* ws = (float*)d_ws;

  float* U = ws;
  float* Qa = U + NN * STRIDE;
  float* Qb = Qa + NN * STRIDE;
  float* Gy = Qb + NN * STRIDE;
  float* gtab = Gy + NN * STRIDE;
  float* partial = gtab + 96;
  float* cepad = partial + 64;
  _Float16* QTa = (_Float16*)(cepad + 64);
  _Float16* QTb = QTa + NRUN * 192;

  k_setup<<<NBLK, 256, 0, stream>>>(logits, labels, image, U, Qa, QTa, QTb,
                                    gtab, partial);

  const float* qi = Qa;
  float* qo = Qb;
  const _Float16* qti = QTa;
  _Float16* qto = QTb;
  const int gblk = NN * STRIDE / 256;  // 864
  for (int it = 0; it < 5; ++it) {
    k_gauss_y<<<gblk, 256, 0, stream>>>(qi, Gy, gtab);
    k_bilat<<<576, 512, 0, stream>>>(U, qi, Gy, qti, gtab, qo, qto, partial,
                                     (float*)d_out, it == 4);
    qi = qo;
    qo = (qo == Qb) ? Qa : Qb;
    const _Float16* tmp = qti;
    qti = qto;
    qto = (_Float16*)tmp;
  }
}